// Round 1
// baseline (3359.371 us; speedup 1.0000x reference)
//
#include <hip/hip_runtime.h>
#include <hip/hip_bf16.h>
#include <math.h>

#define BS 2
#define NHEADS 8
#define HD 32
#define DIM 256
#define S_MAIN 1536
#define S_AUX 768
#define SM_TOT 3072   // concat of main mods 0,1
#define S_TOT 4608    // 1536+1536+768+768

// ---- workspace layout (float offsets) ----
// Qm/Km/Vm: [2][8][3072][32]   = 1,572,864 floats each
// Qa/Ka/Va: [2mods][2][8][768][32] = 786,432 floats each
// AO (attention out, merged heads): [2][4608][256] = 2,359,296 floats
#define QM_OFF 0
#define KM_OFF 1572864
#define VM_OFF 3145728
#define QA_OFF 4718592
#define KA_OFF 5505024
#define VA_OFF 6291456
#define AO_OFF 7077888
// total = 9,437,184 floats = 37.75 MB of d_ws

// ---------------------------------------------------------------------------
// Kernel 1: per-modality QKV projection (x @ Wqkv[m] + bqkv[m]) fused with the
// reshape(bs,s,3,8,32) split + scatter into [b][h][s][d] Q/K/V buffers.
// 64x64 output tile, 256 threads, 4x4 per thread, K staged 16 at a time.
// ---------------------------------------------------------------------------
__global__ __launch_bounds__(256) void qkv_proj_kernel(
    const float* __restrict__ x0, const float* __restrict__ x1,
    const float* __restrict__ x2, const float* __restrict__ x3,
    const float* __restrict__ Wqkv, const float* __restrict__ bqkv,
    float* __restrict__ ws)
{
    const int m  = blockIdx.z;
    const int rt = blockIdx.y;
    const int ct = blockIdx.x;
    const int s_m   = (m < 2) ? S_MAIN : S_AUX;
    const int nrows = BS * s_m;            // 3072 or 1536
    if (rt * 64 >= nrows) return;

    const float* x    = (m == 0) ? x0 : (m == 1) ? x1 : (m == 2) ? x2 : x3;
    const float* W    = Wqkv + m * (DIM * 3 * DIM);
    const float* bias = bqkv + m * (3 * DIM);

    __shared__ float As[16][68];  // [k][row], pad 68 to spread banks
    __shared__ float Bs[16][64];  // [k][col]

    const int t  = threadIdx.x;
    const int tx = t & 15;
    const int ty = t >> 4;
    const int r0 = rt * 64;
    const int c0 = ct * 64;

    float acc[4][4] = {};

    for (int kk = 0; kk < DIM; kk += 16) {
        {
            const int ka = t & 15;
            const int rr = (t >> 4) << 2;
            #pragma unroll
            for (int i = 0; i < 4; ++i)
                As[ka][rr + i] = x[(r0 + rr + i) * DIM + kk + ka];
            const int c  = t & 63;
            const int kb = t >> 6;
            #pragma unroll
            for (int i = 0; i < 4; ++i) {
                const int k2 = kb * 4 + i;
                Bs[k2][c] = W[(kk + k2) * (3 * DIM) + c0 + c];
            }
        }
        __syncthreads();
        #pragma unroll
        for (int k = 0; k < 16; ++k) {
            const float4 av = *(const float4*)&As[k][ty << 2];
            const float4 bv = *(const float4*)&Bs[k][tx << 2];
            const float aa[4] = {av.x, av.y, av.z, av.w};
            const float bb[4] = {bv.x, bv.y, bv.z, bv.w};
            #pragma unroll
            for (int i = 0; i < 4; ++i)
                #pragma unroll
                for (int j = 0; j < 4; ++j)
                    acc[i][j] = fmaf(aa[i], bb[j], acc[i][j]);
        }
        __syncthreads();
    }

    // scatter-store: col c -> (which, head, d); 4 consecutive cols stay inside
    // one 32-wide head block since tx*4 is 4-aligned -> contiguous float4.
    const int cbase = c0 + (tx << 2);
    const int which = cbase >> 8;
    const int head  = (cbase >> 5) & 7;
    const int dd    = cbase & 31;
    float* dst;
    if (m < 2)
        dst = ws + (which == 0 ? QM_OFF : which == 1 ? KM_OFF : VM_OFF);
    else
        dst = ws + (which == 0 ? QA_OFF : which == 1 ? KA_OFF : VA_OFF);
    const float b0 = bias[cbase + 0], b1 = bias[cbase + 1];
    const float b2 = bias[cbase + 2], b3 = bias[cbase + 3];

    #pragma unroll
    for (int i = 0; i < 4; ++i) {
        const int row = r0 + (ty << 2) + i;
        const int b   = (row >= s_m) ? 1 : 0;
        const int s   = row - (b ? s_m : 0);
        int base;
        if (m < 2)
            base = ((b * NHEADS + head) * SM_TOT + (s + m * S_MAIN)) * HD + dd;
        else
            base = ((((m - 2) * BS + b) * NHEADS + head) * S_AUX + s) * HD + dd;
        float4 v;
        v.x = acc[i][0] + b0;
        v.y = acc[i][1] + b1;
        v.z = acc[i][2] + b2;
        v.w = acc[i][3] + b3;
        *(float4*)(dst + base) = v;
    }
}

// ---------------------------------------------------------------------------
// Kernel 2: attention. One wave (64 lanes) handles TWO consecutive q-rows of
// one (b,h). Keys distributed across lanes; each lane keeps an independent
// online softmax (m,l,acc[32]) per row; a single 64-lane butterfly merge at
// the end. Aux modalities iterate 2 key segments: main KV then own KV.
// ---------------------------------------------------------------------------
__global__ __launch_bounds__(256) void attn_kernel(float* __restrict__ ws)
{
    const int widx = (blockIdx.x << 2) + (threadIdx.x >> 6);  // q-row-pair id
    const int lane = threadIdx.x & 63;

    const float* qptr;
    const float* kp0; const float* vp0;
    const float* kp1; const float* vp1;
    int n1, orow0, ocol;

    const int NP_MAIN = BS * NHEADS * SM_TOT / 2;  // 24576 pairs
    if (widx < NP_MAIN) {
        const int b  = widx / (NHEADS * SM_TOT / 2);
        const int r  = widx % (NHEADS * SM_TOT / 2);
        const int h  = r / (SM_TOT / 2);
        const int q0 = (r % (SM_TOT / 2)) << 1;
        qptr = ws + QM_OFF + ((b * NHEADS + h) * SM_TOT + q0) * HD;
        kp0  = ws + KM_OFF + (b * NHEADS + h) * SM_TOT * HD;
        vp0  = ws + VM_OFF + (b * NHEADS + h) * SM_TOT * HD;
        kp1  = nullptr; vp1 = nullptr; n1 = 0;
        orow0 = b * S_TOT + q0;        // main output rows = concat(mod0,mod1)
        ocol  = h * HD;
    } else {
        const int w2  = widx - NP_MAIN;
        const int mod = w2 / (BS * NHEADS * S_AUX / 2);
        const int r   = w2 % (BS * NHEADS * S_AUX / 2);
        const int b   = r / (NHEADS * S_AUX / 2);
        const int r2  = r % (NHEADS * S_AUX / 2);
        const int h   = r2 / (S_AUX / 2);
        const int q0  = (r2 % (S_AUX / 2)) << 1;
        qptr = ws + QA_OFF + (((mod * BS + b) * NHEADS + h) * S_AUX + q0) * HD;
        kp0  = ws + KM_OFF + (b * NHEADS + h) * SM_TOT * HD;
        vp0  = ws + VM_OFF + (b * NHEADS + h) * SM_TOT * HD;
        kp1  = ws + KA_OFF + ((mod * BS + b) * NHEADS + h) * S_AUX * HD;
        vp1  = ws + VA_OFF + ((mod * BS + b) * NHEADS + h) * S_AUX * HD;
        n1   = S_AUX;
        orow0 = b * S_TOT + SM_TOT + mod * S_AUX + q0;
        ocol  = h * HD;
    }

    const float scale = 0.17677669529663687f;  // 1/sqrt(32)
    float q0v[32], q1v[32];
    #pragma unroll
    for (int i = 0; i < 8; ++i) {
        const float4 t0 = *(const float4*)(qptr + i * 4);
        const float4 t1 = *(const float4*)(qptr + HD + i * 4);
        q0v[4*i+0] = t0.x * scale; q0v[4*i+1] = t0.y * scale;
        q0v[4*i+2] = t0.z * scale; q0v[4*i+3] = t0.w * scale;
        q1v[4*i+0] = t1.x * scale; q1v[4*i+1] = t1.y * scale;
        q1v[4*i+2] = t1.z * scale; q1v[4*i+3] = t1.w * scale;
    }

    float m0 = -1e30f, l0 = 0.f, m1 = -1e30f, l1 = 0.f;
    float acc0[32] = {}, acc1[32] = {};

    #pragma unroll 1
    for (int seg = 0; seg < 2; ++seg) {
        const float* kp = seg ? kp1 : kp0;
        const float* vp = seg ? vp1 : vp0;
        const int    n  = seg ? n1  : SM_TOT;
        for (int key = lane; key < n; key += 64) {
            const float* kr = kp + key * HD;
            float s0a = 0.f, s0b = 0.f, s1a = 0.f, s1b = 0.f;  // 2 chains/row
            #pragma unroll
            for (int i = 0; i < 8; ++i) {
                const float4 kv = *(const float4*)(kr + i * 4);
                s0a = fmaf(q0v[4*i+0], kv.x, s0a);
                s0b = fmaf(q0v[4*i+1], kv.y, s0b);
                s0a = fmaf(q0v[4*i+2], kv.z, s0a);
                s0b = fmaf(q0v[4*i+3], kv.w, s0b);
                s1a = fmaf(q1v[4*i+0], kv.x, s1a);
                s1b = fmaf(q1v[4*i+1], kv.y, s1b);
                s1a = fmaf(q1v[4*i+2], kv.z, s1a);
                s1b = fmaf(q1v[4*i+3], kv.w, s1b);
            }
            const float s0 = s0a + s0b;
            const float s1 = s1a + s1b;

            float p0, p1;
            if (s0 > m0) {
                const float sc = __expf(m0 - s0);
                l0 *= sc;
                #pragma unroll
                for (int d = 0; d < 32; ++d) acc0[d] *= sc;
                m0 = s0; p0 = 1.f;
            } else {
                p0 = __expf(s0 - m0);
            }
            l0 += p0;
            if (s1 > m1) {
                const float sc = __expf(m1 - s1);
                l1 *= sc;
                #pragma unroll
                for (int d = 0; d < 32; ++d) acc1[d] *= sc;
                m1 = s1; p1 = 1.f;
            } else {
                p1 = __expf(s1 - m1);
            }
            l1 += p1;

            const float* vr = vp + key * HD;
            #pragma unroll
            for (int i = 0; i < 8; ++i) {
                const float4 vv = *(const float4*)(vr + i * 4);
                acc0[4*i+0] = fmaf(p0, vv.x, acc0[4*i+0]);
                acc0[4*i+1] = fmaf(p0, vv.y, acc0[4*i+1]);
                acc0[4*i+2] = fmaf(p0, vv.z, acc0[4*i+2]);
                acc0[4*i+3] = fmaf(p0, vv.w, acc0[4*i+3]);
                acc1[4*i+0] = fmaf(p1, vv.x, acc1[4*i+0]);
                acc1[4*i+1] = fmaf(p1, vv.y, acc1[4*i+1]);
                acc1[4*i+2] = fmaf(p1, vv.z, acc1[4*i+2]);
                acc1[4*i+3] = fmaf(p1, vv.w, acc1[4*i+3]);
            }
        }
    }

    // 64-lane butterfly merge of (m,l,acc[32]) per row
    #pragma unroll
    for (int off = 1; off < 64; off <<= 1) {
        {
            const float mo = __shfl_xor(m0, off);
            const float lo = __shfl_xor(l0, off);
            const float nm = fmaxf(m0, mo);
            const float sa = __expf(m0 - nm);
            const float sb = __expf(mo - nm);
            l0 = l0 * sa + lo * sb;
            #pragma unroll
            for (int d = 0; d < 32; ++d)
                acc0[d] = acc0[d] * sa + __shfl_xor(acc0[d], off) * sb;
            m0 = nm;
        }
        {
            const float mo = __shfl_xor(m1, off);
            const float lo = __shfl_xor(l1, off);
            const float nm = fmaxf(m1, mo);
            const float sa = __expf(m1 - nm);
            const float sb = __expf(mo - nm);
            l1 = l1 * sa + lo * sb;
            #pragma unroll
            for (int d = 0; d < 32; ++d)
                acc1[d] = acc1[d] * sa + __shfl_xor(acc1[d], off) * sb;
            m1 = nm;
        }
    }

    const float inv0 = 1.f / l0;
    const float inv1 = 1.f / l1;
    // select acc[lane] without runtime register indexing (rule #20)
    float o0 = 0.f, o1 = 0.f;
    #pragma unroll
    for (int d = 0; d < 32; ++d) {
        o0 = (lane == d) ? acc0[d] : o0;
        o1 = (lane == d) ? acc1[d] : o1;
    }
    if (lane < 32) {
        float* ao = ws + AO_OFF;
        ao[(orow0 + 0) * DIM + ocol + lane] = o0 * inv0;
        ao[(orow0 + 1) * DIM + ocol + lane] = o1 * inv1;
    }
}

// ---------------------------------------------------------------------------
// Kernel 3: output projection AO @ Wproj[mod] + bproj[mod] -> d_out.
// Modality boundaries (1536/3072/3840/4608, per batch) are all multiples of
// 64, so each 64-row tile has a single mod.
// ---------------------------------------------------------------------------
__global__ __launch_bounds__(256) void proj_kernel(
    const float* __restrict__ ws, const float* __restrict__ Wproj,
    const float* __restrict__ bproj, float* __restrict__ out)
{
    const float* A = ws + AO_OFF;
    const int ct = blockIdx.x;
    const int rt = blockIdx.y;
    const int r0 = rt * 64, c0 = ct * 64;
    const int seq = r0 % S_TOT;
    const int mod = (seq < S_MAIN) ? 0 : (seq < SM_TOT) ? 1
                  : (seq < SM_TOT + S_AUX) ? 2 : 3;
    const float* W    = Wproj + mod * DIM * DIM;
    const float* bias = bproj + mod * DIM;

    __shared__ float As[16][68];
    __shared__ float Bs[16][64];
    const int t  = threadIdx.x;
    const int tx = t & 15;
    const int ty = t >> 4;

    float acc[4][4] = {};

    for (int kk = 0; kk < DIM; kk += 16) {
        {
            const int ka = t & 15;
            const int rr = (t >> 4) << 2;
            #pragma unroll
            for (int i = 0; i < 4; ++i)
                As[ka][rr + i] = A[(r0 + rr + i) * DIM + kk + ka];
            const int c  = t & 63;
            const int kb = t >> 6;
            #pragma unroll
            for (int i = 0; i < 4; ++i) {
                const int k2 = kb * 4 + i;
                Bs[k2][c] = W[(kk + k2) * DIM + c0 + c];
            }
        }
        __syncthreads();
        #pragma unroll
        for (int k = 0; k < 16; ++k) {
            const float4 av = *(const float4*)&As[k][ty << 2];
            const float4 bv = *(const float4*)&Bs[k][tx << 2];
            const float aa[4] = {av.x, av.y, av.z, av.w};
            const float bb[4] = {bv.x, bv.y, bv.z, bv.w};
            #pragma unroll
            for (int i = 0; i < 4; ++i)
                #pragma unroll
                for (int j = 0; j < 4; ++j)
                    acc[i][j] = fmaf(aa[i], bb[j], acc[i][j]);
        }
        __syncthreads();
    }

    const int c = c0 + (tx << 2);
    const float b0 = bias[c + 0], b1 = bias[c + 1];
    const float b2 = bias[c + 2], b3 = bias[c + 3];
    #pragma unroll
    for (int i = 0; i < 4; ++i) {
        const int row = r0 + (ty << 2) + i;
        float4 v;
        v.x = acc[i][0] + b0;
        v.y = acc[i][1] + b1;
        v.z = acc[i][2] + b2;
        v.w = acc[i][3] + b3;
        *(float4*)(out + row * DIM + c) = v;
    }
}

extern "C" void kernel_launch(void* const* d_in, const int* in_sizes, int n_in,
                              void* d_out, int out_size, void* d_ws, size_t ws_size,
                              hipStream_t stream)
{
    const float* x0    = (const float*)d_in[0];
    const float* x1    = (const float*)d_in[1];
    const float* x2    = (const float*)d_in[2];
    const float* x3    = (const float*)d_in[3];
    const float* Wqkv  = (const float*)d_in[4];
    const float* bqkv  = (const float*)d_in[5];
    const float* Wproj = (const float*)d_in[6];
    const float* bproj = (const float*)d_in[7];
    float* ws  = (float*)d_ws;
    float* out = (float*)d_out;

    // 1) QKV projections + scatter (grid: 12 col-tiles x 48 row-tiles x 4 mods;
    //    aux mods early-exit above row-tile 24)
    qkv_proj_kernel<<<dim3(12, 48, 4), 256, 0, stream>>>(
        x0, x1, x2, x3, Wqkv, bqkv, ws);

    // 2) attention: 36864 q-row pairs, 4 waves/block
    attn_kernel<<<dim3(9216), 256, 0, stream>>>(ws);

    // 3) output projection: 4 col-tiles x 144 row-tiles
    proj_kernel<<<dim3(4, 144), 256, 0, stream>>>(ws, Wproj, bproj, out);
}

// Round 2
// 330.219 us; speedup vs baseline: 10.1732x; 10.1732x over previous
//
#include <hip/hip_runtime.h>
#include <hip/hip_bf16.h>
#include <math.h>

#define BS 2
#define NHEADS 8
#define HD 32
#define DIM 256
#define S_MAIN 1536
#define S_AUX 768
#define SM_TOT 3072
#define S_TOT 4608

typedef _Float16 f16x8 __attribute__((ext_vector_type(8)));
typedef _Float16 f16x4 __attribute__((ext_vector_type(4)));
typedef float    f32x4 __attribute__((ext_vector_type(4)));

#define ATT_SCALE 0.17677669529663687f  // 1/sqrt(32)

// ---- workspace layout ----
// halves (from byte 0):
//   Qm/Km: [2][8][3072][32]      = 1,572,864 halves each
//   VmT:   [2][8][32][3072]      = 1,572,864
//   Qa/Ka: [2mod][2][8][768][32] =   786,432 each
//   VaT:   [2mod][2][8][32][768] =   786,432
#define QM_H  0
#define KM_H  1572864
#define VMT_H 3145728
#define QA_H  4718592
#define KA_H  5505024
#define VAT_H 6291456
// halves end at 7,077,888 halves = 14,155,776 bytes
// AO (fp32, merged heads) [2][4608][256] at float offset:
#define AO_F  3538944
// total ws use = 14.2MB + 9.4MB = 23.6 MB

// ---------------------------------------------------------------------------
// Kernel 1: QKV projection (fp32 GEMM) fused with split + fp16 convert +
// scatter. Q pre-scaled by 1/sqrt(32). V stored transposed [bh][d][s].
// ---------------------------------------------------------------------------
__global__ __launch_bounds__(256) void qkv_proj_kernel(
    const float* __restrict__ x0, const float* __restrict__ x1,
    const float* __restrict__ x2, const float* __restrict__ x3,
    const float* __restrict__ Wqkv, const float* __restrict__ bqkv,
    _Float16* __restrict__ wsh)
{
    const int m  = blockIdx.z;
    const int rt = blockIdx.y;
    const int ct = blockIdx.x;
    const int s_m   = (m < 2) ? S_MAIN : S_AUX;
    const int nrows = BS * s_m;
    if (rt * 64 >= nrows) return;

    const float* x    = (m == 0) ? x0 : (m == 1) ? x1 : (m == 2) ? x2 : x3;
    const float* W    = Wqkv + m * (DIM * 3 * DIM);
    const float* bias = bqkv + m * (3 * DIM);

    __shared__ float As[16][68];
    __shared__ float Bs[16][64];

    const int t  = threadIdx.x;
    const int tx = t & 15;
    const int ty = t >> 4;
    const int r0 = rt * 64;
    const int c0 = ct * 64;

    float acc[4][4] = {};

    for (int kk = 0; kk < DIM; kk += 16) {
        {
            const int ka = t & 15;
            const int rr = (t >> 4) << 2;
            #pragma unroll
            for (int i = 0; i < 4; ++i)
                As[ka][rr + i] = x[(r0 + rr + i) * DIM + kk + ka];
            const int c  = t & 63;
            const int kb = t >> 6;
            #pragma unroll
            for (int i = 0; i < 4; ++i) {
                const int k2 = kb * 4 + i;
                Bs[k2][c] = W[(kk + k2) * (3 * DIM) + c0 + c];
            }
        }
        __syncthreads();
        #pragma unroll
        for (int k = 0; k < 16; ++k) {
            const float4 av = *(const float4*)&As[k][ty << 2];
            const float4 bv = *(const float4*)&Bs[k][tx << 2];
            const float aa[4] = {av.x, av.y, av.z, av.w};
            const float bb[4] = {bv.x, bv.y, bv.z, bv.w};
            #pragma unroll
            for (int i = 0; i < 4; ++i)
                #pragma unroll
                for (int j = 0; j < 4; ++j)
                    acc[i][j] = fmaf(aa[i], bb[j], acc[i][j]);
        }
        __syncthreads();
    }

    const int cbase = c0 + (tx << 2);
    const int which = cbase >> 8;       // 0=Q 1=K 2=V
    const int head  = (cbase >> 5) & 7;
    const int dd    = cbase & 31;
    const float b0 = bias[cbase + 0], b1 = bias[cbase + 1];
    const float b2 = bias[cbase + 2], b3 = bias[cbase + 3];
    const float qs = (which == 0) ? ATT_SCALE : 1.0f;

    #pragma unroll
    for (int i = 0; i < 4; ++i) {
        const int row = r0 + (ty << 2) + i;
        const int b   = (row >= s_m) ? 1 : 0;
        const int s   = row - (b ? s_m : 0);
        float v0 = (acc[i][0] + b0) * qs;
        float v1 = (acc[i][1] + b1) * qs;
        float v2 = (acc[i][2] + b2) * qs;
        float v3 = (acc[i][3] + b3) * qs;

        if (which < 2) {
            // Q/K: [bh][s][32] contiguous halves
            _Float16* dst;
            int base;
            if (m < 2) {
                dst  = wsh + (which == 0 ? QM_H : KM_H);
                base = ((b * NHEADS + head) * SM_TOT + (s + m * S_MAIN)) * HD + dd;
            } else {
                dst  = wsh + (which == 0 ? QA_H : KA_H);
                base = ((((m - 2) * BS + b) * NHEADS + head) * S_AUX + s) * HD + dd;
            }
            f16x4 hv;
            hv[0] = (_Float16)v0; hv[1] = (_Float16)v1;
            hv[2] = (_Float16)v2; hv[3] = (_Float16)v3;
            *(f16x4*)(dst + base) = hv;
        } else {
            // V transposed: [bh][d][s], stride S between d's
            _Float16* dst;
            int base, stride;
            if (m < 2) {
                dst    = wsh + VMT_H;
                base   = ((b * NHEADS + head) * HD + dd) * SM_TOT + (s + m * S_MAIN);
                stride = SM_TOT;
            } else {
                dst    = wsh + VAT_H;
                base   = ((((m - 2) * BS + b) * NHEADS + head) * HD + dd) * S_AUX + s;
                stride = S_AUX;
            }
            dst[base + 0 * stride] = (_Float16)v0;
            dst[base + 1 * stride] = (_Float16)v1;
            dst[base + 2 * stride] = (_Float16)v2;
            dst[base + 3 * stride] = (_Float16)v3;
        }
    }
}

// ---------------------------------------------------------------------------
// Kernel 2: flash attention, fp16 MFMA (16x16x32), fp32 accum.
// One wave = one 16-row Q tile. Key tiles of 32. Fragment layouts:
//   A: row = lane&15, k = 8*(lane>>4)+i   (8 contiguous halves -> dwordx4)
//   B: col = lane&15, k = 8*(lane>>4)+i
//   C/D: col = lane&15, row = 4*(lane>>4)+reg   [verified, learn_hip m89/m91]
// P relayout C->A goes through padded LDS (2-way bank aliasing only = free).
// ---------------------------------------------------------------------------
__global__ __launch_bounds__(256) void attn_mfma_kernel(
    _Float16* __restrict__ wsh, float* __restrict__ wsf)
{
    __shared__ _Float16 plds_all[4][16][40];
    const int wid  = threadIdx.x >> 6;
    const int lane = threadIdx.x & 63;
    const int g    = lane >> 4;
    const int c    = lane & 15;
    _Float16 (*pl)[40] = plds_all[wid];

    const int w = blockIdx.x * 4 + wid;

    const _Float16 *qp, *kp0, *vt0, *kp1, *vt1;
    int n1, vs1, orow0, ocol;

    if (w < 3072) {                      // main modalities
        const int b  = w / 1536;         // 8*192 tiles per batch
        const int h  = (w / 192) & 7;
        const int q0 = (w % 192) * 16;
        const int bh = b * NHEADS + h;
        qp  = wsh + QM_H  + (bh * SM_TOT + q0) * HD;
        kp0 = wsh + KM_H  + bh * SM_TOT * HD;
        vt0 = wsh + VMT_H + bh * HD * SM_TOT;
        kp1 = nullptr; vt1 = nullptr; n1 = 0; vs1 = 0;
        orow0 = b * S_TOT + q0;
        ocol  = h * HD;
    } else {                             // aux modalities
        const int w2  = w - 3072;
        const int mod = w2 / 768;        // 2*8*48 tiles per mod
        const int r   = w2 % 768;
        const int b   = r / 384;
        const int h   = (r / 48) & 7;
        const int q0  = (r % 48) * 16;
        const int mbh = (mod * BS + b) * NHEADS + h;
        const int bh  = b * NHEADS + h;
        qp  = wsh + QA_H  + (mbh * S_AUX + q0) * HD;
        kp0 = wsh + KM_H  + bh * SM_TOT * HD;
        vt0 = wsh + VMT_H + bh * HD * SM_TOT;
        kp1 = wsh + KA_H  + mbh * S_AUX * HD;
        vt1 = wsh + VAT_H + mbh * HD * S_AUX;
        n1  = S_AUX; vs1 = S_AUX;
        orow0 = b * S_TOT + SM_TOT + mod * S_AUX + q0;
        ocol  = h * HD;
    }

    const f16x8 qfrag = *(const f16x8*)(qp + c * HD + g * 8);

    f32x4 o0 = {0.f, 0.f, 0.f, 0.f}, o1 = {0.f, 0.f, 0.f, 0.f};
    float mrow[4] = {-1e30f, -1e30f, -1e30f, -1e30f};
    float lrow[4] = {0.f, 0.f, 0.f, 0.f};

    #pragma unroll 1
    for (int seg = 0; seg < 2; ++seg) {
        const _Float16* kp = seg ? kp1 : kp0;
        const _Float16* vt = seg ? vt1 : vt0;
        const int n  = seg ? n1  : SM_TOT;
        const int vs = seg ? vs1 : SM_TOT;
        if (n == 0) break;

        #pragma unroll 1
        for (int key0 = 0; key0 < n; key0 += 32) {
            const f16x8 kf0 = *(const f16x8*)(kp + (key0 + c) * HD + g * 8);
            const f16x8 kf1 = *(const f16x8*)(kp + (key0 + 16 + c) * HD + g * 8);
            const f16x8 vf0 = *(const f16x8*)(vt + c * vs + key0 + g * 8);
            const f16x8 vf1 = *(const f16x8*)(vt + (16 + c) * vs + key0 + g * 8);

            f32x4 s0 = __builtin_amdgcn_mfma_f32_16x16x32_f16(
                qfrag, kf0, (f32x4){0.f, 0.f, 0.f, 0.f}, 0, 0, 0);
            f32x4 s1 = __builtin_amdgcn_mfma_f32_16x16x32_f16(
                qfrag, kf1, (f32x4){0.f, 0.f, 0.f, 0.f}, 0, 0, 0);

            float p0[4], p1[4];
            #pragma unroll
            for (int r = 0; r < 4; ++r) {
                float tm = fmaxf(s0[r], s1[r]);
                tm = fmaxf(tm, __shfl_xor(tm, 1));
                tm = fmaxf(tm, __shfl_xor(tm, 2));
                tm = fmaxf(tm, __shfl_xor(tm, 4));
                tm = fmaxf(tm, __shfl_xor(tm, 8));
                const float mnew = fmaxf(mrow[r], tm);
                const float corr = __expf(mrow[r] - mnew);
                mrow[r] = mnew;
                p0[r] = __expf(s0[r] - mnew);
                p1[r] = __expf(s1[r] - mnew);
                float rs = p0[r] + p1[r];
                rs += __shfl_xor(rs, 1);
                rs += __shfl_xor(rs, 2);
                rs += __shfl_xor(rs, 4);
                rs += __shfl_xor(rs, 8);
                lrow[r] = lrow[r] * corr + rs;
                o0[r] *= corr;
                o1[r] *= corr;
            }

            // P: C-layout (row 4g+r, col c / c+16) -> LDS -> A-layout read
            #pragma unroll
            for (int r = 0; r < 4; ++r) {
                pl[4 * g + r][c]      = (_Float16)p0[r];
                pl[4 * g + r][c + 16] = (_Float16)p1[r];
            }
            const f16x8 pa = *(const f16x8*)&pl[c][g * 8];

            o0 = __builtin_amdgcn_mfma_f32_16x16x32_f16(pa, vf0, o0, 0, 0, 0);
            o1 = __builtin_amdgcn_mfma_f32_16x16x32_f16(pa, vf1, o1, 0, 0, 0);
        }
    }

    float* ao = wsf + AO_F;
    #pragma unroll
    for (int r = 0; r < 4; ++r) {
        const float inv = 1.0f / lrow[r];
        const int row = orow0 + 4 * g + r;
        ao[row * DIM + ocol + c]      = o0[r] * inv;
        ao[row * DIM + ocol + 16 + c] = o1[r] * inv;
    }
}

// ---------------------------------------------------------------------------
// Kernel 3: output projection AO @ Wproj[mod] + bproj[mod] -> d_out (fp32)
// ---------------------------------------------------------------------------
__global__ __launch_bounds__(256) void proj_kernel(
    const float* __restrict__ wsf, const float* __restrict__ Wproj,
    const float* __restrict__ bproj, float* __restrict__ out)
{
    const float* A = wsf + AO_F;
    const int ct = blockIdx.x;
    const int rt = blockIdx.y;
    const int r0 = rt * 64, c0 = ct * 64;
    const int seq = r0 % S_TOT;
    const int mod = (seq < S_MAIN) ? 0 : (seq < SM_TOT) ? 1
                  : (seq < SM_TOT + S_AUX) ? 2 : 3;
    const float* W    = Wproj + mod * DIM * DIM;
    const float* bias = bproj + mod * DIM;

    __shared__ float As[16][68];
    __shared__ float Bs[16][64];
    const int t  = threadIdx.x;
    const int tx = t & 15;
    const int ty = t >> 4;

    float acc[4][4] = {};

    for (int kk = 0; kk < DIM; kk += 16) {
        {
            const int ka = t & 15;
            const int rr = (t >> 4) << 2;
            #pragma unroll
            for (int i = 0; i < 4; ++i)
                As[ka][rr + i] = A[(r0 + rr + i) * DIM + kk + ka];
            const int c  = t & 63;
            const int kb = t >> 6;
            #pragma unroll
            for (int i = 0; i < 4; ++i) {
                const int k2 = kb * 4 + i;
                Bs[k2][c] = W[(kk + k2) * DIM + c0 + c];
            }
        }
        __syncthreads();
        #pragma unroll
        for (int k = 0; k < 16; ++k) {
            const float4 av = *(const float4*)&As[k][ty << 2];
            const float4 bv = *(const float4*)&Bs[k][tx << 2];
            const float aa[4] = {av.x, av.y, av.z, av.w};
            const float bb[4] = {bv.x, bv.y, bv.z, bv.w};
            #pragma unroll
            for (int i = 0; i < 4; ++i)
                #pragma unroll
                for (int j = 0; j < 4; ++j)
                    acc[i][j] = fmaf(aa[i], bb[j], acc[i][j]);
        }
        __syncthreads();
    }

    const int c = c0 + (tx << 2);
    const float b0 = bias[c + 0], b1 = bias[c + 1];
    const float b2 = bias[c + 2], b3 = bias[c + 3];
    #pragma unroll
    for (int i = 0; i < 4; ++i) {
        const int row = r0 + (ty << 2) + i;
        float4 v;
        v.x = acc[i][0] + b0;
        v.y = acc[i][1] + b1;
        v.z = acc[i][2] + b2;
        v.w = acc[i][3] + b3;
        *(float4*)(out + row * DIM + c) = v;
    }
}

extern "C" void kernel_launch(void* const* d_in, const int* in_sizes, int n_in,
                              void* d_out, int out_size, void* d_ws, size_t ws_size,
                              hipStream_t stream)
{
    const float* x0    = (const float*)d_in[0];
    const float* x1    = (const float*)d_in[1];
    const float* x2    = (const float*)d_in[2];
    const float* x3    = (const float*)d_in[3];
    const float* Wqkv  = (const float*)d_in[4];
    const float* bqkv  = (const float*)d_in[5];
    const float* Wproj = (const float*)d_in[6];
    const float* bproj = (const float*)d_in[7];
    _Float16* wsh = (_Float16*)d_ws;
    float*    wsf = (float*)d_ws;
    float*    out = (float*)d_out;

    qkv_proj_kernel<<<dim3(12, 48, 4), 256, 0, stream>>>(
        x0, x1, x2, x3, Wqkv, bqkv, wsh);

    // 4608 Q-tiles (3072 main + 1536 aux), 4 waves/block
    attn_mfma_kernel<<<dim3(1152), 256, 0, stream>>>(wsh, wsf);

    proj_kernel<<<dim3(4, 144), 256, 0, stream>>>(wsf, Wproj, bproj, out);
}

// Round 3
// 309.203 us; speedup vs baseline: 10.8646x; 1.0680x over previous
//
#include <hip/hip_runtime.h>
#include <hip/hip_bf16.h>
#include <math.h>

#define BS 2
#define NHEADS 8
#define HD 32
#define DIM 256
#define S_MAIN 1536
#define S_AUX 768
#define SM_TOT 3072
#define S_TOT 4608

typedef _Float16 f16x8 __attribute__((ext_vector_type(8)));
typedef _Float16 f16x4 __attribute__((ext_vector_type(4)));
typedef float    f32x4 __attribute__((ext_vector_type(4)));

// 1/sqrt(32) * log2(e): Q pre-scaled so softmax runs in exp2 domain
#define QK_SCALE 0.25503491f

// ---- workspace layout ----
// halves (from byte 0):
//   Qm/Km: [2][8][3072][32]      = 1,572,864 halves each
//   VmT:   [2][8][32][3072]      = 1,572,864
//   Qa/Ka: [2mod][2][8][768][32] =   786,432 each
//   VaT:   [2mod][2][8][32][768] =   786,432
#define QM_H  0
#define KM_H  1572864
#define VMT_H 3145728
#define QA_H  4718592
#define KA_H  5505024
#define VAT_H 6291456
// halves end at 14,155,776 bytes; AO (fp32) [2][4608][256] after:
#define AO_F  3538944

// ---------------------------------------------------------------------------
// Kernel 1: QKV projection (fp32 GEMM) fused with split + fp16 convert +
// scatter. Q pre-scaled by QK_SCALE. V stored transposed [bh][d][s].
// ---------------------------------------------------------------------------
__global__ __launch_bounds__(256) void qkv_proj_kernel(
    const float* __restrict__ x0, const float* __restrict__ x1,
    const float* __restrict__ x2, const float* __restrict__ x3,
    const float* __restrict__ Wqkv, const float* __restrict__ bqkv,
    _Float16* __restrict__ wsh)
{
    const int m  = blockIdx.z;
    const int rt = blockIdx.y;
    const int ct = blockIdx.x;
    const int s_m   = (m < 2) ? S_MAIN : S_AUX;
    const int nrows = BS * s_m;
    if (rt * 64 >= nrows) return;

    const float* x    = (m == 0) ? x0 : (m == 1) ? x1 : (m == 2) ? x2 : x3;
    const float* W    = Wqkv + m * (DIM * 3 * DIM);
    const float* bias = bqkv + m * (3 * DIM);

    __shared__ float As[16][68];
    __shared__ float Bs[16][64];

    const int t  = threadIdx.x;
    const int tx = t & 15;
    const int ty = t >> 4;
    const int r0 = rt * 64;
    const int c0 = ct * 64;

    float acc[4][4] = {};

    for (int kk = 0; kk < DIM; kk += 16) {
        {
            const int ka = t & 15;
            const int rr = (t >> 4) << 2;
            #pragma unroll
            for (int i = 0; i < 4; ++i)
                As[ka][rr + i] = x[(r0 + rr + i) * DIM + kk + ka];
            const int c  = t & 63;
            const int kb = t >> 6;
            #pragma unroll
            for (int i = 0; i < 4; ++i) {
                const int k2 = kb * 4 + i;
                Bs[k2][c] = W[(kk + k2) * (3 * DIM) + c0 + c];
            }
        }
        __syncthreads();
        #pragma unroll
        for (int k = 0; k < 16; ++k) {
            const float4 av = *(const float4*)&As[k][ty << 2];
            const float4 bv = *(const float4*)&Bs[k][tx << 2];
            const float aa[4] = {av.x, av.y, av.z, av.w};
            const float bb[4] = {bv.x, bv.y, bv.z, bv.w};
            #pragma unroll
            for (int i = 0; i < 4; ++i)
                #pragma unroll
                for (int j = 0; j < 4; ++j)
                    acc[i][j] = fmaf(aa[i], bb[j], acc[i][j]);
        }
        __syncthreads();
    }

    const int cbase = c0 + (tx << 2);
    const int which = cbase >> 8;       // 0=Q 1=K 2=V
    const int head  = (cbase >> 5) & 7;
    const int dd    = cbase & 31;
    const float b0 = bias[cbase + 0], b1 = bias[cbase + 1];
    const float b2 = bias[cbase + 2], b3 = bias[cbase + 3];
    const float qs = (which == 0) ? QK_SCALE : 1.0f;

    #pragma unroll
    for (int i = 0; i < 4; ++i) {
        const int row = r0 + (ty << 2) + i;
        const int b   = (row >= s_m) ? 1 : 0;
        const int s   = row - (b ? s_m : 0);
        float v0 = (acc[i][0] + b0) * qs;
        float v1 = (acc[i][1] + b1) * qs;
        float v2 = (acc[i][2] + b2) * qs;
        float v3 = (acc[i][3] + b3) * qs;

        if (which < 2) {
            _Float16* dst;
            int base;
            if (m < 2) {
                dst  = wsh + (which == 0 ? QM_H : KM_H);
                base = ((b * NHEADS + head) * SM_TOT + (s + m * S_MAIN)) * HD + dd;
            } else {
                dst  = wsh + (which == 0 ? QA_H : KA_H);
                base = ((((m - 2) * BS + b) * NHEADS + head) * S_AUX + s) * HD + dd;
            }
            f16x4 hv;
            hv[0] = (_Float16)v0; hv[1] = (_Float16)v1;
            hv[2] = (_Float16)v2; hv[3] = (_Float16)v3;
            *(f16x4*)(dst + base) = hv;
        } else {
            _Float16* dst;
            int base, stride;
            if (m < 2) {
                dst    = wsh + VMT_H;
                base   = ((b * NHEADS + head) * HD + dd) * SM_TOT + (s + m * S_MAIN);
                stride = SM_TOT;
            } else {
                dst    = wsh + VAT_H;
                base   = ((((m - 2) * BS + b) * NHEADS + head) * HD + dd) * S_AUX + s;
                stride = S_AUX;
            }
            dst[base + 0 * stride] = (_Float16)v0;
            dst[base + 1 * stride] = (_Float16)v1;
            dst[base + 2 * stride] = (_Float16)v2;
            dst[base + 3 * stride] = (_Float16)v3;
        }
    }
}

// ---------------------------------------------------------------------------
// Kernel 2: flash attention, swapped-operand MFMA, zero LDS.
//   S^T = mfma(A=K, B=Q): D col=lane&15 = q-row, row=4g+r = key index.
//   K rows loaded with permutation pi(c)=8*(c>>2)+(c&3) (and pi+4) so the
//   S^T regs land exactly in PV's B-operand layout (k=8g+i) after fp16 cvt.
//   O^T = mfma(A=V^T, B=P^T): D col=q-row, row=d -> contiguous float4 store.
//   Softmax fully lane-local per q-row; row reduce = reg tree + 2 shfls.
// ---------------------------------------------------------------------------
__global__ __launch_bounds__(256) void attn_mfma_kernel(
    const _Float16* __restrict__ wsh, float* __restrict__ wsf)
{
    const int wid  = threadIdx.x >> 6;
    const int lane = threadIdx.x & 63;
    const int g    = lane >> 4;
    const int c    = lane & 15;

    const int w = blockIdx.x * 4 + wid;

    const _Float16 *qp, *kp0, *vt0, *kp1, *vt1;
    int n1, vs1, orow0, ocol;

    if (w < 3072) {                      // main modalities
        const int b  = w / 1536;
        const int h  = (w / 192) & 7;
        const int q0 = (w % 192) * 16;
        const int bh = b * NHEADS + h;
        qp  = wsh + QM_H  + (bh * SM_TOT + q0) * HD;
        kp0 = wsh + KM_H  + bh * SM_TOT * HD;
        vt0 = wsh + VMT_H + bh * HD * SM_TOT;
        kp1 = nullptr; vt1 = nullptr; n1 = 0; vs1 = 0;
        orow0 = b * S_TOT + q0;
        ocol  = h * HD;
    } else {                             // aux modalities
        const int w2  = w - 3072;
        const int mod = w2 / 768;
        const int r   = w2 % 768;
        const int b   = r / 384;
        const int h   = (r / 48) & 7;
        const int q0  = (r % 48) * 16;
        const int mbh = (mod * BS + b) * NHEADS + h;
        const int bh  = b * NHEADS + h;
        qp  = wsh + QA_H  + (mbh * S_AUX + q0) * HD;
        kp0 = wsh + KM_H  + bh * SM_TOT * HD;
        vt0 = wsh + VMT_H + bh * HD * SM_TOT;
        kp1 = wsh + KA_H  + mbh * S_AUX * HD;
        vt1 = wsh + VAT_H + mbh * HD * S_AUX;
        n1  = S_AUX; vs1 = S_AUX;
        orow0 = b * S_TOT + SM_TOT + mod * S_AUX + q0;
        ocol  = h * HD;
    }

    // Q as B-operand: col = c = q-row, k = 8g+i
    const f16x8 qfrag = *(const f16x8*)(qp + c * HD + g * 8);

    // permuted key-row offsets for the A-operand of S^T
    const int pc    = ((c >> 2) << 3) + (c & 3);       // pi(c)
    const int koff0 = pc * HD + g * 8;                 // keys 8g+0..3 -> regs
    const int koff1 = (pc + 4) * HD + g * 8;           // keys 8g+4..7

    f32x4 ot0 = {0.f, 0.f, 0.f, 0.f};   // O^T(d=4g+r,      q=c)
    f32x4 ot1 = {0.f, 0.f, 0.f, 0.f};   // O^T(d=16+4g+r,   q=c)
    float mrow = -1e30f, lrow = 0.f;

    #pragma unroll 1
    for (int seg = 0; seg < 2; ++seg) {
        const _Float16* kp = seg ? kp1 : kp0;
        const _Float16* vt = seg ? vt1 : vt0;
        const int n  = seg ? n1  : SM_TOT;
        const int vs = seg ? vs1 : SM_TOT;
        if (n == 0) break;

        #pragma unroll 1
        for (int key0 = 0; key0 < n; key0 += 64) {
            const _Float16* kb = kp + key0 * HD;
            const f16x8 kf0 = *(const f16x8*)(kb + koff0);
            const f16x8 kf1 = *(const f16x8*)(kb + koff1);
            const f16x8 kf2 = *(const f16x8*)(kb + 32 * HD + koff0);
            const f16x8 kf3 = *(const f16x8*)(kb + 32 * HD + koff1);
            const _Float16* vb = vt + key0 + g * 8;
            const f16x8 va0 = *(const f16x8*)(vb + c * vs);
            const f16x8 va1 = *(const f16x8*)(vb + (16 + c) * vs);
            const f16x8 vb0 = *(const f16x8*)(vb + c * vs + 32);
            const f16x8 vb1 = *(const f16x8*)(vb + (16 + c) * vs + 32);

            f32x4 s0 = __builtin_amdgcn_mfma_f32_16x16x32_f16(
                kf0, qfrag, (f32x4){0.f, 0.f, 0.f, 0.f}, 0, 0, 0);
            f32x4 s1 = __builtin_amdgcn_mfma_f32_16x16x32_f16(
                kf1, qfrag, (f32x4){0.f, 0.f, 0.f, 0.f}, 0, 0, 0);
            f32x4 s2 = __builtin_amdgcn_mfma_f32_16x16x32_f16(
                kf2, qfrag, (f32x4){0.f, 0.f, 0.f, 0.f}, 0, 0, 0);
            f32x4 s3 = __builtin_amdgcn_mfma_f32_16x16x32_f16(
                kf3, qfrag, (f32x4){0.f, 0.f, 0.f, 0.f}, 0, 0, 0);

            // row max (tree, lane-local) + 2 shfls across g groups
            float ta = fmaxf(fmaxf(s0[0], s0[1]), fmaxf(s0[2], s0[3]));
            float tb = fmaxf(fmaxf(s1[0], s1[1]), fmaxf(s1[2], s1[3]));
            float tc = fmaxf(fmaxf(s2[0], s2[1]), fmaxf(s2[2], s2[3]));
            float td = fmaxf(fmaxf(s3[0], s3[1]), fmaxf(s3[2], s3[3]));
            float tm = fmaxf(fmaxf(ta, tb), fmaxf(tc, td));
            tm = fmaxf(tm, __shfl_xor(tm, 16));
            tm = fmaxf(tm, __shfl_xor(tm, 32));

            const float mnew = fmaxf(mrow, tm);
            const float corr = __builtin_amdgcn_exp2f(mrow - mnew);
            mrow = mnew;

            float p0[4], p1[4], p2[4], p3[4];
            #pragma unroll
            for (int r = 0; r < 4; ++r) {
                p0[r] = __builtin_amdgcn_exp2f(s0[r] - mnew);
                p1[r] = __builtin_amdgcn_exp2f(s1[r] - mnew);
                p2[r] = __builtin_amdgcn_exp2f(s2[r] - mnew);
                p3[r] = __builtin_amdgcn_exp2f(s3[r] - mnew);
            }
            float rs = ((p0[0] + p0[1]) + (p0[2] + p0[3]))
                     + ((p1[0] + p1[1]) + (p1[2] + p1[3]))
                     + ((p2[0] + p2[1]) + (p2[2] + p2[3]))
                     + ((p3[0] + p3[1]) + (p3[2] + p3[3]));
            rs += __shfl_xor(rs, 16);
            rs += __shfl_xor(rs, 32);
            lrow = lrow * corr + rs;

            #pragma unroll
            for (int r = 0; r < 4; ++r) { ot0[r] *= corr; ot1[r] *= corr; }

            // P^T as B-operand, assembled in-lane thanks to pi()
            f16x8 pb0, pb1;
            #pragma unroll
            for (int r = 0; r < 4; ++r) {
                pb0[r]     = (_Float16)p0[r];
                pb0[r + 4] = (_Float16)p1[r];
                pb1[r]     = (_Float16)p2[r];
                pb1[r + 4] = (_Float16)p3[r];
            }

            ot0 = __builtin_amdgcn_mfma_f32_16x16x32_f16(va0, pb0, ot0, 0, 0, 0);
            ot1 = __builtin_amdgcn_mfma_f32_16x16x32_f16(va1, pb0, ot1, 0, 0, 0);
            ot0 = __builtin_amdgcn_mfma_f32_16x16x32_f16(vb0, pb1, ot0, 0, 0, 0);
            ot1 = __builtin_amdgcn_mfma_f32_16x16x32_f16(vb1, pb1, ot1, 0, 0, 0);
        }
    }

    const float inv = 1.0f / lrow;
    float* ao = wsf + AO_F + (orow0 + c) * DIM + ocol;
    float4 w0, w1;
    w0.x = ot0[0] * inv; w0.y = ot0[1] * inv;
    w0.z = ot0[2] * inv; w0.w = ot0[3] * inv;
    w1.x = ot1[0] * inv; w1.y = ot1[1] * inv;
    w1.z = ot1[2] * inv; w1.w = ot1[3] * inv;
    *(float4*)(ao + 4 * g)      = w0;
    *(float4*)(ao + 16 + 4 * g) = w1;
}

// ---------------------------------------------------------------------------
// Kernel 3: output projection AO @ Wproj[mod] + bproj[mod] -> d_out (fp32)
// ---------------------------------------------------------------------------
__global__ __launch_bounds__(256) void proj_kernel(
    const float* __restrict__ wsf, const float* __restrict__ Wproj,
    const float* __restrict__ bproj, float* __restrict__ out)
{
    const float* A = wsf + AO_F;
    const int ct = blockIdx.x;
    const int rt = blockIdx.y;
    const int r0 = rt * 64, c0 = ct * 64;
    const int seq = r0 % S_TOT;
    const int mod = (seq < S_MAIN) ? 0 : (seq < SM_TOT) ? 1
                  : (seq < SM_TOT + S_AUX) ? 2 : 3;
    const float* W    = Wproj + mod * DIM * DIM;
    const float* bias = bproj + mod * DIM;

    __shared__ float As[16][68];
    __shared__ float Bs[16][64];
    const int t  = threadIdx.x;
    const int tx = t & 15;
    const int ty = t >> 4;

    float acc[4][4] = {};

    for (int kk = 0; kk < DIM; kk += 16) {
        {
            const int ka = t & 15;
            const int rr = (t >> 4) << 2;
            #pragma unroll
            for (int i = 0; i < 4; ++i)
                As[ka][rr + i] = A[(r0 + rr + i) * DIM + kk + ka];
            const int c  = t & 63;
            const int kb = t >> 6;
            #pragma unroll
            for (int i = 0; i < 4; ++i) {
                const int k2 = kb * 4 + i;
                Bs[k2][c] = W[(kk + k2) * DIM + c0 + c];
            }
        }
        __syncthreads();
        #pragma unroll
        for (int k = 0; k < 16; ++k) {
            const float4 av = *(const float4*)&As[k][ty << 2];
            const float4 bv = *(const float4*)&Bs[k][tx << 2];
            const float aa[4] = {av.x, av.y, av.z, av.w};
            const float bb[4] = {bv.x, bv.y, bv.z, bv.w};
            #pragma unroll
            for (int i = 0; i < 4; ++i)
                #pragma unroll
                for (int j = 0; j < 4; ++j)
                    acc[i][j] = fmaf(aa[i], bb[j], acc[i][j]);
        }
        __syncthreads();
    }

    const int c = c0 + (tx << 2);
    const float b0 = bias[c + 0], b1 = bias[c + 1];
    const float b2 = bias[c + 2], b3 = bias[c + 3];
    #pragma unroll
    for (int i = 0; i < 4; ++i) {
        const int row = r0 + (ty << 2) + i;
        float4 v;
        v.x = acc[i][0] + b0;
        v.y = acc[i][1] + b1;
        v.z = acc[i][2] + b2;
        v.w = acc[i][3] + b3;
        *(float4*)(out + row * DIM + c) = v;
    }
}

extern "C" void kernel_launch(void* const* d_in, const int* in_sizes, int n_in,
                              void* d_out, int out_size, void* d_ws, size_t ws_size,
                              hipStream_t stream)
{
    const float* x0    = (const float*)d_in[0];
    const float* x1    = (const float*)d_in[1];
    const float* x2    = (const float*)d_in[2];
    const float* x3    = (const float*)d_in[3];
    const float* Wqkv  = (const float*)d_in[4];
    const float* bqkv  = (const float*)d_in[5];
    const float* Wproj = (const float*)d_in[6];
    const float* bproj = (const float*)d_in[7];
    _Float16* wsh = (_Float16*)d_ws;
    float*    wsf = (float*)d_ws;
    float*    out = (float*)d_out;

    qkv_proj_kernel<<<dim3(12, 48, 4), 256, 0, stream>>>(
        x0, x1, x2, x3, Wqkv, bqkv, wsh);

    attn_mfma_kernel<<<dim3(1152), 256, 0, stream>>>(wsh, wsf);

    proj_kernel<<<dim3(4, 144), 256, 0, stream>>>(wsf, Wproj, bproj, out);
}

// Round 4
// 306.593 us; speedup vs baseline: 10.9571x; 1.0085x over previous
//
#include <hip/hip_runtime.h>
#include <hip/hip_bf16.h>
#include <math.h>

#define BS 2
#define NHEADS 8
#define HD 32
#define DIM 256
#define S_MAIN 1536
#define S_AUX 768
#define SM_TOT 3072
#define S_TOT 4608

typedef _Float16 f16x8 __attribute__((ext_vector_type(8)));
typedef _Float16 f16x4 __attribute__((ext_vector_type(4)));
typedef float    f32x4 __attribute__((ext_vector_type(4)));

// 1/sqrt(32) * log2(e): Q pre-scaled so softmax runs in exp2 domain
#define QK_SCALE 0.25503491f

// ---- workspace layout ----
// halves (from byte 0):
//   Qm/Km: [2][8][3072][32]      = 1,572,864 halves each
//   VmT:   [2][8][32][3072]      = 1,572,864
//   Qa/Ka: [2mod][2][8][768][32] =   786,432 each
//   VaT:   [2mod][2][8][32][768] =   786,432
#define QM_H  0
#define KM_H  1572864
#define VMT_H 3145728
#define QA_H  4718592
#define KA_H  5505024
#define VAT_H 6291456
// halves end at 14,155,776 bytes; AO (fp32) [2][4608][256] after:
#define AO_F  3538944

// ---------------------------------------------------------------------------
// Kernel 1: QKV projection (fp32 GEMM) fused with split + fp16 convert +
// scatter. Q pre-scaled by QK_SCALE. V stored transposed [bh][d][s].
// ---------------------------------------------------------------------------
__global__ __launch_bounds__(256) void qkv_proj_kernel(
    const float* __restrict__ x0, const float* __restrict__ x1,
    const float* __restrict__ x2, const float* __restrict__ x3,
    const float* __restrict__ Wqkv, const float* __restrict__ bqkv,
    _Float16* __restrict__ wsh)
{
    const int m  = blockIdx.z;
    const int rt = blockIdx.y;
    const int ct = blockIdx.x;
    const int s_m   = (m < 2) ? S_MAIN : S_AUX;
    const int nrows = BS * s_m;
    if (rt * 64 >= nrows) return;

    const float* x    = (m == 0) ? x0 : (m == 1) ? x1 : (m == 2) ? x2 : x3;
    const float* W    = Wqkv + m * (DIM * 3 * DIM);
    const float* bias = bqkv + m * (3 * DIM);

    __shared__ float As[16][68];
    __shared__ float Bs[16][64];

    const int t  = threadIdx.x;
    const int tx = t & 15;
    const int ty = t >> 4;
    const int r0 = rt * 64;
    const int c0 = ct * 64;

    float acc[4][4] = {};

    for (int kk = 0; kk < DIM; kk += 16) {
        {
            const int ka = t & 15;
            const int rr = (t >> 4) << 2;
            #pragma unroll
            for (int i = 0; i < 4; ++i)
                As[ka][rr + i] = x[(r0 + rr + i) * DIM + kk + ka];
            const int c  = t & 63;
            const int kb = t >> 6;
            #pragma unroll
            for (int i = 0; i < 4; ++i) {
                const int k2 = kb * 4 + i;
                Bs[k2][c] = W[(kk + k2) * (3 * DIM) + c0 + c];
            }
        }
        __syncthreads();
        #pragma unroll
        for (int k = 0; k < 16; ++k) {
            const float4 av = *(const float4*)&As[k][ty << 2];
            const float4 bv = *(const float4*)&Bs[k][tx << 2];
            const float aa[4] = {av.x, av.y, av.z, av.w};
            const float bb[4] = {bv.x, bv.y, bv.z, bv.w};
            #pragma unroll
            for (int i = 0; i < 4; ++i)
                #pragma unroll
                for (int j = 0; j < 4; ++j)
                    acc[i][j] = fmaf(aa[i], bb[j], acc[i][j]);
        }
        __syncthreads();
    }

    const int cbase = c0 + (tx << 2);
    const int which = cbase >> 8;       // 0=Q 1=K 2=V
    const int head  = (cbase >> 5) & 7;
    const int dd    = cbase & 31;
    const float b0 = bias[cbase + 0], b1 = bias[cbase + 1];
    const float b2 = bias[cbase + 2], b3 = bias[cbase + 3];
    const float qs = (which == 0) ? QK_SCALE : 1.0f;

    #pragma unroll
    for (int i = 0; i < 4; ++i) {
        const int row = r0 + (ty << 2) + i;
        const int b   = (row >= s_m) ? 1 : 0;
        const int s   = row - (b ? s_m : 0);
        float v0 = (acc[i][0] + b0) * qs;
        float v1 = (acc[i][1] + b1) * qs;
        float v2 = (acc[i][2] + b2) * qs;
        float v3 = (acc[i][3] + b3) * qs;

        if (which < 2) {
            _Float16* dst;
            int base;
            if (m < 2) {
                dst  = wsh + (which == 0 ? QM_H : KM_H);
                base = ((b * NHEADS + head) * SM_TOT + (s + m * S_MAIN)) * HD + dd;
            } else {
                dst  = wsh + (which == 0 ? QA_H : KA_H);
                base = ((((m - 2) * BS + b) * NHEADS + head) * S_AUX + s) * HD + dd;
            }
            f16x4 hv;
            hv[0] = (_Float16)v0; hv[1] = (_Float16)v1;
            hv[2] = (_Float16)v2; hv[3] = (_Float16)v3;
            *(f16x4*)(dst + base) = hv;
        } else {
            _Float16* dst;
            int base, stride;
            if (m < 2) {
                dst    = wsh + VMT_H;
                base   = ((b * NHEADS + head) * HD + dd) * SM_TOT + (s + m * S_MAIN);
                stride = SM_TOT;
            } else {
                dst    = wsh + VAT_H;
                base   = ((((m - 2) * BS + b) * NHEADS + head) * HD + dd) * S_AUX + s;
                stride = S_AUX;
            }
            dst[base + 0 * stride] = (_Float16)v0;
            dst[base + 1 * stride] = (_Float16)v1;
            dst[base + 2 * stride] = (_Float16)v2;
            dst[base + 3 * stride] = (_Float16)v3;
        }
    }
}

// ---------------------------------------------------------------------------
// Kernel 2: flash attention, swapped-operand MFMA, zero LDS.
//   S^T = mfma(A=K, B=Q): D col=lane&15 = q-row, row=4g+r = key index.
//   K rows loaded with permutation pi(c)=8*(c>>2)+(c&3) (and pi+4) so the
//   S^T regs land exactly in PV's B-operand layout (k=8g+i) after fp16 cvt.
//   O^T = mfma(A=V^T, B=P^T): D col=q-row, row=d -> contiguous float4 store.
//   Softmax fully lane-local per q-row; row reduce = reg tree + 2 shfls.
// ---------------------------------------------------------------------------
__global__ __launch_bounds__(256) void attn_mfma_kernel(
    const _Float16* __restrict__ wsh, float* __restrict__ wsf)
{
    const int wid  = threadIdx.x >> 6;
    const int lane = threadIdx.x & 63;
    const int g    = lane >> 4;
    const int c    = lane & 15;

    const int w = blockIdx.x * 4 + wid;

    const _Float16 *qp, *kp0, *vt0, *kp1, *vt1;
    int n1, vs1, orow0, ocol;

    if (w < 3072) {                      // main modalities
        const int b  = w / 1536;
        const int h  = (w / 192) & 7;
        const int q0 = (w % 192) * 16;
        const int bh = b * NHEADS + h;
        qp  = wsh + QM_H  + (bh * SM_TOT + q0) * HD;
        kp0 = wsh + KM_H  + bh * SM_TOT * HD;
        vt0 = wsh + VMT_H + bh * HD * SM_TOT;
        kp1 = nullptr; vt1 = nullptr; n1 = 0; vs1 = 0;
        orow0 = b * S_TOT + q0;
        ocol  = h * HD;
    } else {                             // aux modalities
        const int w2  = w - 3072;
        const int mod = w2 / 768;
        const int r   = w2 % 768;
        const int b   = r / 384;
        const int h   = (r / 48) & 7;
        const int q0  = (r % 48) * 16;
        const int mbh = (mod * BS + b) * NHEADS + h;
        const int bh  = b * NHEADS + h;
        qp  = wsh + QA_H  + (mbh * S_AUX + q0) * HD;
        kp0 = wsh + KM_H  + bh * SM_TOT * HD;
        vt0 = wsh + VMT_H + bh * HD * SM_TOT;
        kp1 = wsh + KA_H  + mbh * S_AUX * HD;
        vt1 = wsh + VAT_H + mbh * HD * S_AUX;
        n1  = S_AUX; vs1 = S_AUX;
        orow0 = b * S_TOT + SM_TOT + mod * S_AUX + q0;
        ocol  = h * HD;
    }

    // Q as B-operand: col = c = q-row, k = 8g+i
    const f16x8 qfrag = *(const f16x8*)(qp + c * HD + g * 8);

    // permuted key-row offsets for the A-operand of S^T
    const int pc    = ((c >> 2) << 3) + (c & 3);       // pi(c)
    const int koff0 = pc * HD + g * 8;                 // keys 8g+0..3 -> regs
    const int koff1 = (pc + 4) * HD + g * 8;           // keys 8g+4..7

    f32x4 ot0 = {0.f, 0.f, 0.f, 0.f};   // O^T(d=4g+r,      q=c)
    f32x4 ot1 = {0.f, 0.f, 0.f, 0.f};   // O^T(d=16+4g+r,   q=c)
    float mrow = -1e30f, lrow = 0.f;

    #pragma unroll 1
    for (int seg = 0; seg < 2; ++seg) {
        const _Float16* kp = seg ? kp1 : kp0;
        const _Float16* vt = seg ? vt1 : vt0;
        const int n  = seg ? n1  : SM_TOT;
        const int vs = seg ? vs1 : SM_TOT;
        if (n == 0) break;

        #pragma unroll 1
        for (int key0 = 0; key0 < n; key0 += 64) {
            const _Float16* kb = kp + key0 * HD;
            const f16x8 kf0 = *(const f16x8*)(kb + koff0);
            const f16x8 kf1 = *(const f16x8*)(kb + koff1);
            const f16x8 kf2 = *(const f16x8*)(kb + 32 * HD + koff0);
            const f16x8 kf3 = *(const f16x8*)(kb + 32 * HD + koff1);
            const _Float16* vb = vt + key0 + g * 8;
            const f16x8 va0 = *(const f16x8*)(vb + c * vs);
            const f16x8 va1 = *(const f16x8*)(vb + (16 + c) * vs);
            const f16x8 vb0 = *(const f16x8*)(vb + c * vs + 32);
            const f16x8 vb1 = *(const f16x8*)(vb + (16 + c) * vs + 32);

            f32x4 s0 = __builtin_amdgcn_mfma_f32_16x16x32_f16(
                kf0, qfrag, (f32x4){0.f, 0.f, 0.f, 0.f}, 0, 0, 0);
            f32x4 s1 = __builtin_amdgcn_mfma_f32_16x16x32_f16(
                kf1, qfrag, (f32x4){0.f, 0.f, 0.f, 0.f}, 0, 0, 0);
            f32x4 s2 = __builtin_amdgcn_mfma_f32_16x16x32_f16(
                kf2, qfrag, (f32x4){0.f, 0.f, 0.f, 0.f}, 0, 0, 0);
            f32x4 s3 = __builtin_amdgcn_mfma_f32_16x16x32_f16(
                kf3, qfrag, (f32x4){0.f, 0.f, 0.f, 0.f}, 0, 0, 0);

            // row max (tree, lane-local) + 2 shfls across g groups
            float ta = fmaxf(fmaxf(s0[0], s0[1]), fmaxf(s0[2], s0[3]));
            float tb = fmaxf(fmaxf(s1[0], s1[1]), fmaxf(s1[2], s1[3]));
            float tc = fmaxf(fmaxf(s2[0], s2[1]), fmaxf(s2[2], s2[3]));
            float td = fmaxf(fmaxf(s3[0], s3[1]), fmaxf(s3[2], s3[3]));
            float tm = fmaxf(fmaxf(ta, tb), fmaxf(tc, td));
            tm = fmaxf(tm, __shfl_xor(tm, 16));
            tm = fmaxf(tm, __shfl_xor(tm, 32));

            const float mnew = fmaxf(mrow, tm);
            const float corr = __builtin_amdgcn_exp2f(mrow - mnew);
            mrow = mnew;

            float p0[4], p1[4], p2[4], p3[4];
            #pragma unroll
            for (int r = 0; r < 4; ++r) {
                p0[r] = __builtin_amdgcn_exp2f(s0[r] - mnew);
                p1[r] = __builtin_amdgcn_exp2f(s1[r] - mnew);
                p2[r] = __builtin_amdgcn_exp2f(s2[r] - mnew);
                p3[r] = __builtin_amdgcn_exp2f(s3[r] - mnew);
            }
            float rs = ((p0[0] + p0[1]) + (p0[2] + p0[3]))
                     + ((p1[0] + p1[1]) + (p1[2] + p1[3]))
                     + ((p2[0] + p2[1]) + (p2[2] + p2[3]))
                     + ((p3[0] + p3[1]) + (p3[2] + p3[3]));
            rs += __shfl_xor(rs, 16);
            rs += __shfl_xor(rs, 32);
            lrow = lrow * corr + rs;

            #pragma unroll
            for (int r = 0; r < 4; ++r) { ot0[r] *= corr; ot1[r] *= corr; }

            // P^T as B-operand, assembled in-lane thanks to pi()
            f16x8 pb0, pb1;
            #pragma unroll
            for (int r = 0; r < 4; ++r) {
                pb0[r]     = (_Float16)p0[r];
                pb0[r + 4] = (_Float16)p1[r];
                pb1[r]     = (_Float16)p2[r];
                pb1[r + 4] = (_Float16)p3[r];
            }

            ot0 = __builtin_amdgcn_mfma_f32_16x16x32_f16(va0, pb0, ot0, 0, 0, 0);
            ot1 = __builtin_amdgcn_mfma_f32_16x16x32_f16(va1, pb0, ot1, 0, 0, 0);
            ot0 = __builtin_amdgcn_mfma_f32_16x16x32_f16(vb0, pb1, ot0, 0, 0, 0);
            ot1 = __builtin_amdgcn_mfma_f32_16x16x32_f16(vb1, pb1, ot1, 0, 0, 0);
        }
    }

    const float inv = 1.0f / lrow;
    float* ao = wsf + AO_F + (orow0 + c) * DIM + ocol;
    float4 w0, w1;
    w0.x = ot0[0] * inv; w0.y = ot0[1] * inv;
    w0.z = ot0[2] * inv; w0.w = ot0[3] * inv;
    w1.x = ot1[0] * inv; w1.y = ot1[1] * inv;
    w1.z = ot1[2] * inv; w1.w = ot1[3] * inv;
    *(float4*)(ao + 4 * g)      = w0;
    *(float4*)(ao + 16 + 4 * g) = w1;
}

// ---------------------------------------------------------------------------
// Kernel 3: output projection AO @ Wproj[mod] + bproj[mod] -> d_out (fp32)
// ---------------------------------------------------------------------------
__global__ __launch_bounds__(256) void proj_kernel(
    const float* __restrict__ wsf, const float* __restrict__ Wproj,
    const float* __restrict__ bproj, float* __restrict__ out)
{
    const float* A = wsf + AO_F;
    const int ct = blockIdx.x;
    const int rt = blockIdx.y;
    const int r0 = rt * 64, c0 = ct * 64;
    const int seq = r0 % S_TOT;
    const int mod = (seq < S_MAIN) ? 0 : (seq < SM_TOT) ? 1
                  : (seq < SM_TOT + S_AUX) ? 2 : 3;
    const float* W    = Wproj + mod * DIM * DIM;
    const float* bias = bproj + mod * DIM;

    __shared__ float As[16][68];
    __shared__ float Bs[16][64];
    const int t  = threadIdx.x;
    const int tx = t & 15;
    const int ty = t >> 4;

    float acc[4][4] = {};

    for (int kk = 0; kk < DIM; kk += 16) {
        {
            const int ka = t & 15;
            const int rr = (t >> 4) << 2;
            #pragma unroll
            for (int i = 0; i < 4; ++i)
                As[ka][rr + i] = A[(r0 + rr + i) * DIM + kk + ka];
            const int c  = t & 63;
            const int kb = t >> 6;
            #pragma unroll
            for (int i = 0; i < 4; ++i) {
                const int k2 = kb * 4 + i;
                Bs[k2][c] = W[(kk + k2) * DIM + c0 + c];
            }
        }
        __syncthreads();
        #pragma unroll
        for (int k = 0; k < 16; ++k) {
            const float4 av = *(const float4*)&As[k][ty << 2];
            const float4 bv = *(const float4*)&Bs[k][tx << 2];
            const float aa[4] = {av.x, av.y, av.z, av.w};
            const float bb[4] = {bv.x, bv.y, bv.z, bv.w};
            #pragma unroll
            for (int i = 0; i < 4; ++i)
                #pragma unroll
                for (int j = 0; j < 4; ++j)
                    acc[i][j] = fmaf(aa[i], bb[j], acc[i][j]);
        }
        __syncthreads();
    }

    const int c = c0 + (tx << 2);
    const float b0 = bias[c + 0], b1 = bias[c + 1];
    const float b2 = bias[c + 2], b3 = bias[c + 3];
    #pragma unroll
    for (int i = 0; i < 4; ++i) {
        const int row = r0 + (ty << 2) + i;
        float4 v;
        v.x = acc[i][0] + b0;
        v.y = acc[i][1] + b1;
        v.z = acc[i][2] + b2;
        v.w = acc[i][3] + b3;
        *(float4*)(out + row * DIM + c) = v;
    }
}

extern "C" void kernel_launch(void* const* d_in, const int* in_sizes, int n_in,
                              void* d_out, int out_size, void* d_ws, size_t ws_size,
                              hipStream_t stream)
{
    const float* x0    = (const float*)d_in[0];
    const float* x1    = (const float*)d_in[1];
    const float* x2    = (const float*)d_in[2];
    const float* x3    = (const float*)d_in[3];
    const float* Wqkv  = (const float*)d_in[4];
    const float* bqkv  = (const float*)d_in[5];
    const float* Wproj = (const float*)d_in[6];
    const float* bproj = (const float*)d_in[7];
    _Float16* wsh = (_Float16*)d_ws;
    float*    wsf = (float*)d_ws;
    float*    out = (float*)d_out;

    qkv_proj_kernel<<<dim3(12, 48, 4), 256, 0, stream>>>(
        x0, x1, x2, x3, Wqkv, bqkv, wsh);

    attn_mfma_kernel<<<dim3(1152), 256, 0, stream>>>(wsh, wsf);

    proj_kernel<<<dim3(4, 144), 256, 0, stream>>>(wsf, Wproj, bproj, out);
}